// Round 1
// baseline (128.021 us; speedup 1.0000x reference)
//
#include <hip/hip_runtime.h>
#include <hip/hip_bf16.h>

#define NN 4096
#define EMB 256
#define NCH 10
#define TOTD 2560  // NCH*EMB

typedef __attribute__((ext_vector_type(8))) short bf16x8;
typedef __attribute__((ext_vector_type(4))) float f32x4;

// ---------------- kernel 1: partial column sums of F = diag(w^2) E ----------
__global__ __launch_bounds__(256) void colsum_k(const float* __restrict__ E,
                                                const float* __restrict__ w,
                                                float* __restrict__ partial) {
    int col = blockIdx.x * 256 + threadIdx.x;   // 0..2559
    int s   = blockIdx.y;                        // 0..31 (row slice of 128)
    int a0  = s * 128;
    float acc = 0.f;
    for (int r = 0; r < 128; ++r) {
        int a = a0 + r;
        float ww = w[a];
        acc += ww * ww * E[(size_t)a * TOTD + col];
    }
    partial[s * TOTD + col] = acc;
}

// ---------------- kernel 1b: reduce partials -> column means -----------------
__global__ __launch_bounds__(256) void colmean_k(const float* __restrict__ partial,
                                                 float* __restrict__ colmean) {
    int col = blockIdx.x * 256 + threadIdx.x;
    float s = 0.f;
    for (int i = 0; i < 32; ++i) s += partial[i * TOTD + col];
    colmean[col] = s * (1.0f / NN);
}

// ------- kernel 2: G = F - colmean, transposed + bf16:  Gt[d][a] -------------
__global__ __launch_bounds__(256) void transpose_center_k(const float* __restrict__ E,
                                                          const float* __restrict__ w,
                                                          const float* __restrict__ colmean,
                                                          unsigned short* __restrict__ Gt) {
    __shared__ float tile[32][33];
    int d0 = blockIdx.x * 32, a0 = blockIdx.y * 32;
    int tx = threadIdx.x & 31, ty = threadIdx.x >> 5;  // ty in 0..7
#pragma unroll
    for (int r = 0; r < 4; ++r) {
        int a = a0 + ty + r * 8;
        int d = d0 + tx;
        float ww = w[a];
        tile[ty + r * 8][tx] = ww * ww * E[(size_t)a * TOTD + d] - colmean[d];
    }
    __syncthreads();
#pragma unroll
    for (int r = 0; r < 4; ++r) {
        int d = d0 + ty + r * 8;
        int a = a0 + tx;
        float v = tile[tx][ty + r * 8];
        union { __hip_bfloat16 b; unsigned short u; } cv;
        cv.b = __float2bfloat16(v);
        Gt[(size_t)d * NN + a] = cv.u;
    }
}

// ------- kernel 3: per (pair, 64x64 subtile) block: ||(G_i^T G_j)_tile||^2 ---
// 720 blocks = 45 pairs * 16 subtiles. 4 waves split K=4096 into 4x1024,
// each wave computes the full 64x64 tile partial via 16x16x32 bf16 MFMA,
// fragments loaded directly from global (L2/LLC resident), then cross-wave
// LDS reduction, square, block-sum.
__global__ __launch_bounds__(256) void gram_fro_k(const unsigned short* __restrict__ Gt,
                                                  float* __restrict__ pp) {
    int blk = blockIdx.x;
    int pr = blk >> 4, sub = blk & 15;
    // decode pair (i<j) from pr in [0,45)
    int i = 0, rr0 = pr, cnt = NCH - 1;
    while (rr0 >= cnt) { rr0 -= cnt; --cnt; ++i; }
    int j = i + 1 + rr0;
    int sp = sub >> 2, sq = sub & 3;

    int wave = threadIdx.x >> 6, lane = threadIdx.x & 63;
    int m = lane & 15, kg = lane >> 4;

    const unsigned short* Arow = Gt + (size_t)(i * EMB + sp * 64 + m) * NN;
    const unsigned short* Brow = Gt + (size_t)(j * EMB + sq * 64 + m) * NN;
    int k = wave * 1024 + kg * 8;

    f32x4 acc[4][4];
#pragma unroll
    for (int f = 0; f < 4; ++f)
#pragma unroll
        for (int g = 0; g < 4; ++g) acc[f][g] = (f32x4){0.f, 0.f, 0.f, 0.f};

    bf16x8 aC[4], bC[4], aN[4], bN[4];
#pragma unroll
    for (int f = 0; f < 4; ++f) {
        aC[f] = *reinterpret_cast<const bf16x8*>(Arow + (size_t)f * 16 * NN + k);
        bC[f] = *reinterpret_cast<const bf16x8*>(Brow + (size_t)f * 16 * NN + k);
    }
    for (int t = 0; t < 16; ++t) {
#pragma unroll
        for (int f = 0; f < 4; ++f) {
            aN[f] = *reinterpret_cast<const bf16x8*>(Arow + (size_t)f * 16 * NN + k + 32);
            bN[f] = *reinterpret_cast<const bf16x8*>(Brow + (size_t)f * 16 * NN + k + 32);
        }
#pragma unroll
        for (int f = 0; f < 4; ++f)
#pragma unroll
            for (int g = 0; g < 4; ++g)
                acc[f][g] = __builtin_amdgcn_mfma_f32_16x16x32_bf16(aC[f], bC[g], acc[f][g], 0, 0, 0);
        // prefetch k+64 (final iteration over-reads harmlessly into ws scratch)
#pragma unroll
        for (int f = 0; f < 4; ++f) {
            aC[f] = *reinterpret_cast<const bf16x8*>(Arow + (size_t)f * 16 * NN + k + 64);
            bC[f] = *reinterpret_cast<const bf16x8*>(Brow + (size_t)f * 16 * NN + k + 64);
        }
#pragma unroll
        for (int f = 0; f < 4; ++f)
#pragma unroll
            for (int g = 0; g < 4; ++g)
                acc[f][g] = __builtin_amdgcn_mfma_f32_16x16x32_bf16(aN[f], bN[g], acc[f][g], 0, 0, 0);
        k += 64;
    }

    // cross-wave reduce of the 64x64 tile (layout-agnostic: same bijection in
    // every wave, and we only need the sum of squares of the full tile)
    __shared__ float red[64][65];
    __shared__ float sred[256];
    for (int wt = 0; wt < 4; ++wt) {
        if (wave == wt) {
#pragma unroll
            for (int f = 0; f < 4; ++f)
#pragma unroll
                for (int g = 0; g < 4; ++g)
#pragma unroll
                    for (int r = 0; r < 4; ++r) {
                        int row = f * 16 + kg * 4 + r;
                        int col = g * 16 + m;
                        if (wt == 0) red[row][col] = acc[f][g][r];
                        else         red[row][col] += acc[f][g][r];
                    }
        }
        __syncthreads();
    }
    float s = 0.f;
    for (int e = threadIdx.x; e < 4096; e += 256) {
        float v = red[e >> 6][e & 63];
        s += v * v;
    }
    sred[threadIdx.x] = s;
    __syncthreads();
    if (threadIdx.x < 64) {
        s = sred[threadIdx.x] + sred[threadIdx.x + 64] + sred[threadIdx.x + 128] + sred[threadIdx.x + 192];
#pragma unroll
        for (int off = 32; off > 0; off >>= 1) s += __shfl_down(s, off);
        if (threadIdx.x == 0) pp[blk] = s;
    }
}

// ---------------- kernel 4: deterministic final reduction --------------------
__global__ __launch_bounds__(256) void finalize_k(const float* __restrict__ pp,
                                                  float* __restrict__ out) {
    __shared__ float sh[256];
    float s = 0.f;
    for (int idx = threadIdx.x; idx < 720; idx += 256) s += pp[idx];
    sh[threadIdx.x] = s;
    __syncthreads();
    for (int stride = 128; stride > 0; stride >>= 1) {
        if (threadIdx.x < stride) sh[threadIdx.x] += sh[threadIdx.x + stride];
        __syncthreads();
    }
    if (threadIdx.x == 0) out[0] = sh[0] * (1.0f / (4095.0f * 4095.0f));
}

extern "C" void kernel_launch(void* const* d_in, const int* in_sizes, int n_in,
                              void* d_out, int out_size, void* d_ws, size_t ws_size,
                              hipStream_t stream) {
    const float* E = (const float*)d_in[0];   // [4096, 2560] f32
    const float* w = (const float*)d_in[1];   // [4096, 1] f32
    float* out = (float*)d_out;
    char* ws = (char*)d_ws;

    // ws layout (bytes):
    //   Gt       : 0         .. 20971520   (2560 x 4096 bf16)
    //   partial  : 20971520  .. 21299200   (32 x 2560 f32)
    //   colmean  : 21299200  .. 21309440   (2560 f32)
    //   pp       : 21309440  .. 21312320   (720 f32)
    unsigned short* Gt = (unsigned short*)ws;
    float* partial = (float*)(ws + (size_t)20971520);
    float* colmean = (float*)(ws + (size_t)21299200);
    float* pp      = (float*)(ws + (size_t)21309440);

    colsum_k<<<dim3(10, 32), 256, 0, stream>>>(E, w, partial);
    colmean_k<<<10, 256, 0, stream>>>(partial, colmean);
    transpose_center_k<<<dim3(80, 128), 256, 0, stream>>>(E, w, colmean, Gt);
    gram_fro_k<<<720, 256, 0, stream>>>(Gt, pp);
    finalize_k<<<1, 256, 0, stream>>>(pp, out);
}

// Round 2
// 126.111 us; speedup vs baseline: 1.0151x; 1.0151x over previous
//
#include <hip/hip_runtime.h>
#include <hip/hip_bf16.h>

#define NN 4096
#define EMB 256
#define NCH 10
#define TOTD 2560  // NCH*EMB

typedef __attribute__((ext_vector_type(8))) short bf16x8;
typedef __attribute__((ext_vector_type(4))) float f32x4;

// ---------------- kernel 1: partial column sums of F = diag(w^2) E ----------
__global__ __launch_bounds__(256) void colsum_k(const float* __restrict__ E,
                                                const float* __restrict__ w,
                                                float* __restrict__ partial) {
    int col = blockIdx.x * 256 + threadIdx.x;   // 0..2559
    int s   = blockIdx.y;                        // 0..31 (row slice of 128)
    int a0  = s * 128;
    float acc = 0.f;
    for (int r = 0; r < 128; ++r) {
        int a = a0 + r;
        float ww = w[a];
        acc += ww * ww * E[(size_t)a * TOTD + col];
    }
    partial[s * TOTD + col] = acc;
}

// ---------------- kernel 1b: reduce partials -> column means -----------------
__global__ __launch_bounds__(256) void colmean_k(const float* __restrict__ partial,
                                                 float* __restrict__ colmean) {
    int col = blockIdx.x * 256 + threadIdx.x;
    float s = 0.f;
    for (int i = 0; i < 32; ++i) s += partial[i * TOTD + col];
    colmean[col] = s * (1.0f / NN);
}

// ------- kernel 2: G = F - colmean, transposed + bf16:  Gt[d][a] -------------
__global__ __launch_bounds__(256) void transpose_center_k(const float* __restrict__ E,
                                                          const float* __restrict__ w,
                                                          const float* __restrict__ colmean,
                                                          unsigned short* __restrict__ Gt) {
    __shared__ float tile[32][33];
    int d0 = blockIdx.x * 32, a0 = blockIdx.y * 32;
    int tx = threadIdx.x & 31, ty = threadIdx.x >> 5;  // ty in 0..7
#pragma unroll
    for (int r = 0; r < 4; ++r) {
        int a = a0 + ty + r * 8;
        int d = d0 + tx;
        float ww = w[a];
        tile[ty + r * 8][tx] = ww * ww * E[(size_t)a * TOTD + d] - colmean[d];
    }
    __syncthreads();
#pragma unroll
    for (int r = 0; r < 4; ++r) {
        int d = d0 + ty + r * 8;
        int a = a0 + tx;
        float v = tile[tx][ty + r * 8];
        union { __hip_bfloat16 b; unsigned short u; } cv;
        cv.b = __float2bfloat16(v);
        Gt[(size_t)d * NN + a] = cv.u;
    }
}

// ------- kernel 3: per (pair, 64x64 subtile) block: ||(G_i^T G_j)_tile||^2 ---
// 768 blocks (45 pairs * 16 subtiles + 48 idle), 8 waves each. Wave w owns a
// K=512 slice. Full k64-step register double-buffer (prefetch distance = 32
// MFMA). XCD swizzle: all 16 subtiles of a pair land on one XCD (blockIdx%8
// round-robin assumption) for L2 reuse of the pair's two 2MB chunk strips.
#define LOADSTEP(A0, B0, A1, B1, kk)                                           \
    _Pragma("unroll") for (int f = 0; f < 4; ++f) {                            \
        A0[f] = *reinterpret_cast<const bf16x8*>(Arow + (size_t)f * 16 * NN + (kk));      \
        B0[f] = *reinterpret_cast<const bf16x8*>(Brow + (size_t)f * 16 * NN + (kk));      \
        A1[f] = *reinterpret_cast<const bf16x8*>(Arow + (size_t)f * 16 * NN + (kk) + 32); \
        B1[f] = *reinterpret_cast<const bf16x8*>(Brow + (size_t)f * 16 * NN + (kk) + 32); \
    }

#define MFMASTEP(A0, B0, A1, B1)                                               \
    _Pragma("unroll") for (int f = 0; f < 4; ++f)                              \
    _Pragma("unroll") for (int g = 0; g < 4; ++g)                              \
        acc[f][g] = __builtin_amdgcn_mfma_f32_16x16x32_bf16(A0[f], B0[g], acc[f][g], 0, 0, 0); \
    _Pragma("unroll") for (int f = 0; f < 4; ++f)                              \
    _Pragma("unroll") for (int g = 0; g < 4; ++g)                              \
        acc[f][g] = __builtin_amdgcn_mfma_f32_16x16x32_bf16(A1[f], B1[g], acc[f][g], 0, 0, 0);

__global__ __launch_bounds__(512) void gram_fro_k(const unsigned short* __restrict__ Gt,
                                                  float* __restrict__ pp) {
    int x = blockIdx.x & 7;       // intended XCD
    int q = blockIdx.x >> 3;      // 0..95
    int pr = x + 8 * (q >> 4);    // pair id; all 16 subtiles of pr share x
    if (pr >= 45) return;
    int sub = q & 15;
    // decode pair (i<j) from pr in [0,45)
    int i = 0, rr0 = pr, cnt = NCH - 1;
    while (rr0 >= cnt) { rr0 -= cnt; --cnt; ++i; }
    int j = i + 1 + rr0;
    int sp = sub >> 2, sq = sub & 3;

    int wave = threadIdx.x >> 6, lane = threadIdx.x & 63;
    int m = lane & 15, kg = lane >> 4;

    const unsigned short* Arow = Gt + (size_t)(i * EMB + sp * 64 + m) * NN + kg * 8;
    const unsigned short* Brow = Gt + (size_t)(j * EMB + sq * 64 + m) * NN + kg * 8;
    int k0 = wave * 512;

    f32x4 acc[4][4];
#pragma unroll
    for (int f = 0; f < 4; ++f)
#pragma unroll
        for (int g = 0; g < 4; ++g) acc[f][g] = (f32x4){0.f, 0.f, 0.f, 0.f};

    bf16x8 a0[4], b0[4], a1[4], b1[4];      // current k64 step (both halves)
    bf16x8 na0[4], nb0[4], na1[4], nb1[4];  // next k64 step

    LOADSTEP(a0, b0, a1, b1, k0)
#pragma unroll
    for (int t = 0; t < 4; ++t) {
        int kk = k0 + t * 128;
        LOADSTEP(na0, nb0, na1, nb1, kk + 64)
        MFMASTEP(a0, b0, a1, b1)
        if (t < 3) { LOADSTEP(a0, b0, a1, b1, kk + 128) }
        MFMASTEP(na0, nb0, na1, nb1)
    }

    // cross-wave reduce + square. Element bijection per f-pass:
    // (q=g*4+r, lane) <-> one element of rows [f*16,f*16+16) x cols [0,64).
    __shared__ float red[8][16][64];  // 32 KB, bank-conflict-free both phases
    float sqacc = 0.f;
#pragma unroll
    for (int f = 0; f < 4; ++f) {
        __syncthreads();
#pragma unroll
        for (int g = 0; g < 4; ++g)
#pragma unroll
            for (int r = 0; r < 4; ++r)
                red[wave][g * 4 + r][lane] = acc[f][g][r];
        __syncthreads();
#pragma unroll
        for (int e2 = 0; e2 < 2; ++e2) {
            int e = (int)threadIdx.x + e2 * 512;
            int qq = e >> 6, ll = e & 63;
            float s = 0.f;
#pragma unroll
            for (int w8 = 0; w8 < 8; ++w8) s += red[w8][qq][ll];
            sqacc += s * s;
        }
    }

    __shared__ float sred[512];
    sred[threadIdx.x] = sqacc;
    __syncthreads();
    if (threadIdx.x < 64) {
        float s = 0.f;
#pragma unroll
        for (int c = 0; c < 8; ++c) s += sred[threadIdx.x + c * 64];
#pragma unroll
        for (int off = 32; off > 0; off >>= 1) s += __shfl_down(s, off);
        if (threadIdx.x == 0) pp[pr * 16 + sub] = s;
    }
}

// ---------------- kernel 4: deterministic final reduction --------------------
__global__ __launch_bounds__(256) void finalize_k(const float* __restrict__ pp,
                                                  float* __restrict__ out) {
    __shared__ float sh[256];
    float s = 0.f;
    for (int idx = threadIdx.x; idx < 720; idx += 256) s += pp[idx];
    sh[threadIdx.x] = s;
    __syncthreads();
    for (int stride = 128; stride > 0; stride >>= 1) {
        if (threadIdx.x < stride) sh[threadIdx.x] += sh[threadIdx.x + stride];
        __syncthreads();
    }
    if (threadIdx.x == 0) out[0] = sh[0] * (1.0f / (4095.0f * 4095.0f));
}

extern "C" void kernel_launch(void* const* d_in, const int* in_sizes, int n_in,
                              void* d_out, int out_size, void* d_ws, size_t ws_size,
                              hipStream_t stream) {
    const float* E = (const float*)d_in[0];   // [4096, 2560] f32
    const float* w = (const float*)d_in[1];   // [4096, 1] f32
    float* out = (float*)d_out;
    char* ws = (char*)d_ws;

    // ws layout (bytes):
    //   Gt       : 0         .. 20971520   (2560 x 4096 bf16)
    //   partial  : 20971520  .. 21299200   (32 x 2560 f32)
    //   colmean  : 21299200  .. 21309440   (2560 f32)
    //   pp       : 21309440  .. 21312320   (720 f32)
    unsigned short* Gt = (unsigned short*)ws;
    float* partial = (float*)(ws + (size_t)20971520);
    float* colmean = (float*)(ws + (size_t)21299200);
    float* pp      = (float*)(ws + (size_t)21309440);

    colsum_k<<<dim3(10, 32), 256, 0, stream>>>(E, w, partial);
    colmean_k<<<10, 256, 0, stream>>>(partial, colmean);
    transpose_center_k<<<dim3(80, 128), 256, 0, stream>>>(E, w, colmean, Gt);
    gram_fro_k<<<768, 512, 0, stream>>>(Gt, pp);
    finalize_k<<<1, 256, 0, stream>>>(pp, out);
}

// Round 3
// 63.092 us; speedup vs baseline: 2.0291x; 1.9988x over previous
//
#include <hip/hip_runtime.h>
#include <hip/hip_bf16.h>

#define NN 4096
#define EMB 256
#define NCH 10
#define TOTD 2560  // NCH*EMB

typedef __attribute__((ext_vector_type(8))) short bf16x8;
typedef __attribute__((ext_vector_type(4))) float f32x4;

#define AS1 __attribute__((address_space(1)))
#define AS3 __attribute__((address_space(3)))

__device__ __forceinline__ void gload_lds16(const void* g, void* l) {
    __builtin_amdgcn_global_load_lds((const AS1 unsigned int*)g,
                                     (AS3 unsigned int*)l, 16, 0, 0);
}

// ---------------- kernel 1: partial column sums of F = diag(w^2) E ----------
__global__ __launch_bounds__(256) void colsum_k(const float* __restrict__ E,
                                                const float* __restrict__ w,
                                                float* __restrict__ partial) {
    int col = blockIdx.x * 256 + threadIdx.x;   // 0..2559
    int s   = blockIdx.y;                        // 0..31 (row slice of 128)
    int a0  = s * 128;
    float acc = 0.f;
    for (int r = 0; r < 128; ++r) {
        int a = a0 + r;
        float ww = w[a];
        acc += ww * ww * E[(size_t)a * TOTD + col];
    }
    partial[s * TOTD + col] = acc;
}

// ---------------- kernel 1b: reduce partials -> column means -----------------
__global__ __launch_bounds__(256) void colmean_k(const float* __restrict__ partial,
                                                 float* __restrict__ colmean) {
    int col = blockIdx.x * 256 + threadIdx.x;
    float s = 0.f;
    for (int i = 0; i < 32; ++i) s += partial[i * TOTD + col];
    colmean[col] = s * (1.0f / NN);
}

// ------- kernel 2: G = F - colmean, transposed + bf16:  Gt[d][a] -------------
__global__ __launch_bounds__(256) void transpose_center_k(const float* __restrict__ E,
                                                          const float* __restrict__ w,
                                                          const float* __restrict__ colmean,
                                                          unsigned short* __restrict__ Gt) {
    __shared__ float tile[32][33];
    int d0 = blockIdx.x * 32, a0 = blockIdx.y * 32;
    int tx = threadIdx.x & 31, ty = threadIdx.x >> 5;  // ty in 0..7
#pragma unroll
    for (int r = 0; r < 4; ++r) {
        int a = a0 + ty + r * 8;
        int d = d0 + tx;
        float ww = w[a];
        tile[ty + r * 8][tx] = ww * ww * E[(size_t)a * TOTD + d] - colmean[d];
    }
    __syncthreads();
#pragma unroll
    for (int r = 0; r < 4; ++r) {
        int d = d0 + ty + r * 8;
        int a = a0 + tx;
        float v = tile[tx][ty + r * 8];
        union { __hip_bfloat16 b; unsigned short u; } cv;
        cv.b = __float2bfloat16(v);
        Gt[(size_t)d * NN + a] = cv.u;
    }
}

// ------- kernel 3: 180 blocks = 45 pairs x 4 K-slices (K=1024 each) ----------
// 512 threads = 8 waves in a 2(M) x 4(N) grid; each wave computes 128x64 of
// the pair's 256x256 Gram tile. BK=64 double-buffered LDS staging via
// global_load_lds (linear dest) with inverse-swizzled global source; ds_read
// applies the same XOR swizzle -> conflict-free ds_read_b128.
// LDS tile layout: [256 rows][64 bf16] = 128 B/row = 8 slots of 16 B;
// element at (row, slot) holds global (row, slot ^ (row&7)).
__global__ __launch_bounds__(512, 2) void gram_fro_k(const unsigned short* __restrict__ Gt,
                                                     float* __restrict__ pp) {
    int pr = blockIdx.x >> 2;   // pair id 0..44
    int s  = blockIdx.x & 3;    // K-slice
    int i = 0, r0 = pr, cnt = NCH - 1;
    while (r0 >= cnt) { r0 -= cnt; --cnt; ++i; }
    int j = i + 1 + r0;

    const int k0 = s * 1024;
    const int tid  = threadIdx.x;
    const int wave = tid >> 6, lane = tid & 63;
    const int wm = wave >> 2, wn = wave & 3;   // wave grid 2x4
    const int m = lane & 15, kg = lane >> 4;

    __shared__ char lds[131072];   // [buf][A 32K | B 32K]
    __shared__ float sred[512];

    // Staging: issue `is` covers rows is*64 + wave*8 + (lane>>3), slot lane&7.
    // Source column (elements): ((lane&7) ^ (lane>>3)) * 8  (row&7 == lane>>3).
    const int srcCol = ((lane & 7) ^ (lane >> 3)) * 8;
    const unsigned short* gA = Gt + (size_t)(i * EMB + wave * 8 + (lane >> 3)) * NN + k0 + srcCol;
    const unsigned short* gB = Gt + (size_t)(j * EMB + wave * 8 + (lane >> 3)) * NN + k0 + srcCol;
    const int ldsA = wave * 1024;            // + is*8192 (+ buf*65536)
    const int ldsB = 32768 + wave * 1024;

#define STAGE(buf, t)                                                                   \
    do {                                                                                \
        _Pragma("unroll") for (int is = 0; is < 4; ++is) {                              \
            gload_lds16(gA + (size_t)is * 64 * NN + (size_t)(t) * 64,                   \
                        lds + (buf) * 65536 + ldsA + is * 8192);                        \
            gload_lds16(gB + (size_t)is * 64 * NN + (size_t)(t) * 64,                   \
                        lds + (buf) * 65536 + ldsB + is * 8192);                        \
        }                                                                               \
    } while (0)

    f32x4 acc[8][4];
#pragma unroll
    for (int f = 0; f < 8; ++f)
#pragma unroll
        for (int g = 0; g < 4; ++g) acc[f][g] = (f32x4){0.f, 0.f, 0.f, 0.f};

    STAGE(0, 0);
    __syncthreads();

    int buf = 0;
    for (int t = 0; t < 16; ++t) {
        if (t < 15) STAGE(buf ^ 1, t + 1);
        const char* Ab = lds + buf * 65536;
        const char* Bb = lds + buf * 65536 + 32768;
#pragma unroll
        for (int kk = 0; kk < 2; ++kk) {
            bf16x8 af[8], bfr[4];
            const int sl = ((kk * 4 + kg) ^ (m & 7)) * 16;
#pragma unroll
            for (int f = 0; f < 8; ++f)
                af[f] = *(const bf16x8*)(Ab + (wm * 128 + f * 16 + m) * 128 + sl);
#pragma unroll
            for (int g = 0; g < 4; ++g)
                bfr[g] = *(const bf16x8*)(Bb + (wn * 64 + g * 16 + m) * 128 + sl);
#pragma unroll
            for (int f = 0; f < 8; ++f)
#pragma unroll
                for (int g = 0; g < 4; ++g)
                    acc[f][g] = __builtin_amdgcn_mfma_f32_16x16x32_bf16(af[f], bfr[g], acc[f][g], 0, 0, 0);
        }
        __syncthreads();
        buf ^= 1;
    }
#undef STAGE

    // sum of squares (C/D layout-agnostic)
    float sq = 0.f;
#pragma unroll
    for (int f = 0; f < 8; ++f)
#pragma unroll
        for (int g = 0; g < 4; ++g)
#pragma unroll
            for (int r = 0; r < 4; ++r) sq += acc[f][g][r] * acc[f][g][r];

    sred[tid] = sq;
    __syncthreads();
    if (tid < 64) {
        float v = 0.f;
#pragma unroll
        for (int c = 0; c < 8; ++c) v += sred[tid + c * 64];
#pragma unroll
        for (int off = 32; off > 0; off >>= 1) v += __shfl_down(v, off);
        if (tid == 0) pp[blockIdx.x] = v;
    }
}

// ---------------- kernel 4: deterministic final reduction --------------------
__global__ __launch_bounds__(256) void finalize_k(const float* __restrict__ pp,
                                                  float* __restrict__ out) {
    __shared__ float sh[256];
    float s = 0.f;
    for (int idx = threadIdx.x; idx < 180; idx += 256) s += pp[idx];
    sh[threadIdx.x] = s;
    __syncthreads();
    for (int stride = 128; stride > 0; stride >>= 1) {
        if (threadIdx.x < stride) sh[threadIdx.x] += sh[threadIdx.x + stride];
        __syncthreads();
    }
    if (threadIdx.x == 0) out[0] = sh[0] * (1.0f / (4095.0f * 4095.0f));
}

extern "C" void kernel_launch(void* const* d_in, const int* in_sizes, int n_in,
                              void* d_out, int out_size, void* d_ws, size_t ws_size,
                              hipStream_t stream) {
    const float* E = (const float*)d_in[0];   // [4096, 2560] f32
    const float* w = (const float*)d_in[1];   // [4096, 1] f32
    float* out = (float*)d_out;
    char* ws = (char*)d_ws;

    // ws layout (bytes):
    //   Gt       : 0         .. 20971520   (2560 x 4096 bf16)
    //   partial  : 20971520  .. 21299200   (32 x 2560 f32)
    //   colmean  : 21299200  .. 21309440   (2560 f32)
    //   pp       : 21309440  .. 21312320   (180 f32 used)
    unsigned short* Gt = (unsigned short*)ws;
    float* partial = (float*)(ws + (size_t)20971520);
    float* colmean = (float*)(ws + (size_t)21299200);
    float* pp      = (float*)(ws + (size_t)21309440);

    colsum_k<<<dim3(10, 32), 256, 0, stream>>>(E, w, partial);
    colmean_k<<<10, 256, 0, stream>>>(partial, colmean);
    transpose_center_k<<<dim3(80, 128), 256, 0, stream>>>(E, w, colmean, Gt);
    gram_fro_k<<<180, 512, 0, stream>>>(Gt, pp);
    finalize_k<<<1, 256, 0, stream>>>(pp, out);
}

// Round 4
// 51.160 us; speedup vs baseline: 2.5024x; 1.2332x over previous
//
#include <hip/hip_runtime.h>
#include <hip/hip_bf16.h>

#define NN 4096
#define EMB 256
#define NCH 10
#define TOTD 2560  // NCH*EMB

typedef __attribute__((ext_vector_type(8))) short bf16x8;
typedef __attribute__((ext_vector_type(8))) unsigned short u16x8;
typedef __attribute__((ext_vector_type(4))) float f32x4;

#define AS1 __attribute__((address_space(1)))
#define AS3 __attribute__((address_space(3)))

__device__ __forceinline__ void gload_lds16(const void* g, void* l) {
    __builtin_amdgcn_global_load_lds((const AS1 unsigned int*)g,
                                     (AS3 unsigned int*)l, 16, 0, 0);
}

// ---- kernel 1 (fused prep): one pass over E.
// F = w^2 * E ; Gt[d][a] = bf16(F[a][d]) ; csp[ablk][d] = sum_{a in 64-blk} F[a][d]
__global__ __launch_bounds__(256) void prep_k(const float* __restrict__ E,
                                              const float* __restrict__ w,
                                              unsigned short* __restrict__ Gt,
                                              float* __restrict__ csp) {
    __shared__ float tile[64][65];
    const int ab = blockIdx.x, db = blockIdx.y;
    const int a0 = ab * 64, d0 = db * 64;
    const int t = threadIdx.x;
    const int ar = t >> 4, dc = (t & 15) * 4;
#pragma unroll
    for (int r = 0; r < 4; ++r) {
        int a = ar + r * 16;
        float ww = w[a0 + a];
        ww *= ww;
        const float4 v = *reinterpret_cast<const float4*>(E + (size_t)(a0 + a) * TOTD + d0 + dc);
        tile[a][dc + 0] = ww * v.x;
        tile[a][dc + 1] = ww * v.y;
        tile[a][dc + 2] = ww * v.z;
        tile[a][dc + 3] = ww * v.w;
    }
    __syncthreads();
    const int as = (t & 7) * 8;
#pragma unroll
    for (int r = 0; r < 2; ++r) {
        int d = (t >> 3) + r * 32;
        u16x8 u;
#pragma unroll
        for (int e = 0; e < 8; ++e) {
            union { __hip_bfloat16 b; unsigned short s; } cv;
            cv.b = __float2bfloat16(tile[as + e][d]);
            u[e] = cv.s;
        }
        *reinterpret_cast<u16x8*>(Gt + (size_t)(d0 + d) * NN + a0 + as) = u;
    }
    if (t < 64) {
        float s = 0.f;
#pragma unroll 8
        for (int a = 0; a < 64; ++a) s += tile[a][t];
        csp[(size_t)ab * TOTD + d0 + t] = s;
    }
}

// ---- kernel 2: per-slice colsums S[16][2560] and global colmean cm[2560]
__global__ __launch_bounds__(256) void sums_k(const float* __restrict__ csp,
                                              float* __restrict__ S,
                                              float* __restrict__ cm) {
    int d = blockIdx.x * 256 + threadIdx.x;
    float tot = 0.f;
#pragma unroll
    for (int s = 0; s < 16; ++s) {
        float v = 0.f;
#pragma unroll
        for (int b = 0; b < 4; ++b) v += csp[(size_t)(s * 4 + b) * TOTD + d];
        S[(size_t)s * TOTD + d] = v;
        tot += v;
    }
    cm[d] = tot * (1.0f / NN);
}

// ---- kernel 3: 720 blocks = 45 pairs x 16 K-slices (K=256, BK=32 dbuf).
// 8 waves (2Mx4N), wave tile 128x64 of the 256x256 pair tile. Epilogue applies
// the exact per-slice rank-1 centering correction, then sums squares.
// LDS tile [256 rows][4 slots of 16B]; element (row, lslot) holds global
// (row, lslot ^ ((row>>1)&3)) -> conflict-free-ish ds_read_b128 (2-way max).
__global__ __launch_bounds__(512) void gram_fro_k(const unsigned short* __restrict__ Gt,
                                                  const float* __restrict__ S,
                                                  const float* __restrict__ cm,
                                                  float* __restrict__ pp) {
    const int pr = blockIdx.x >> 4, s = blockIdx.x & 15;
    int ci = 0, r0 = pr, cnt = NCH - 1;
    while (r0 >= cnt) { r0 -= cnt; --cnt; ++ci; }
    const int cj = ci + 1 + r0;
    const int k0 = s * 256;

    const int tid = threadIdx.x, wave = tid >> 6, lane = tid & 63;
    const int wm = wave >> 2, wn = wave & 3;
    const int m = lane & 15, kg = lane >> 4;

    __shared__ char lds[65536];   // [buf(2)][A 16K | B 16K]
    __shared__ float sred[512];

    // staging: issue ii covers rows wave*32 + ii*16 + (lane>>2), lds slot lane&3.
    // global source pre-swizzled: gslot = (lane&3) ^ ((row>>1)&3) = (lane&3)^((lane>>3)&3)
    const int gslot = (lane & 3) ^ ((lane >> 3) & 3);
    const unsigned short* gA = Gt + (size_t)(ci * EMB + wave * 32 + (lane >> 2)) * NN + k0 + gslot * 8;
    const unsigned short* gB = Gt + (size_t)(cj * EMB + wave * 32 + (lane >> 2)) * NN + k0 + gslot * 8;
    const int ldsBase = wave * 2048;  // (wave*32 rows) * 64 B

#define STAGE(buf, t)                                                          \
    do {                                                                       \
        _Pragma("unroll") for (int ii = 0; ii < 2; ++ii) {                     \
            gload_lds16(gA + (size_t)ii * 16 * NN + (t) * 32,                  \
                        lds + (buf) * 32768 + ldsBase + ii * 1024);            \
            gload_lds16(gB + (size_t)ii * 16 * NN + (t) * 32,                  \
                        lds + (buf) * 32768 + 16384 + ldsBase + ii * 1024);    \
        }                                                                      \
    } while (0)

    f32x4 acc[8][4];
#pragma unroll
    for (int f = 0; f < 8; ++f)
#pragma unroll
        for (int g = 0; g < 4; ++g) acc[f][g] = (f32x4){0.f, 0.f, 0.f, 0.f};

    STAGE(0, 0);
    __syncthreads();

    int buf = 0;
    const int slotRd = (kg ^ ((m >> 1) & 3)) * 16;
    for (int t = 0; t < 8; ++t) {
        if (t < 7) STAGE(buf ^ 1, t + 1);
        const char* Ab = lds + buf * 32768;
        const char* Bb = Ab + 16384;
        bf16x8 af[8], bfr[4];
#pragma unroll
        for (int f = 0; f < 8; ++f)
            af[f] = *reinterpret_cast<const bf16x8*>(Ab + (wm * 128 + f * 16 + m) * 64 + slotRd);
#pragma unroll
        for (int g = 0; g < 4; ++g)
            bfr[g] = *reinterpret_cast<const bf16x8*>(Bb + (wn * 64 + g * 16 + m) * 64 + slotRd);
#pragma unroll
        for (int f = 0; f < 8; ++f)
#pragma unroll
            for (int g = 0; g < 4; ++g)
                acc[f][g] = __builtin_amdgcn_mfma_f32_16x16x32_bf16(af[f], bfr[g], acc[f][g], 0, 0, 0);
        __syncthreads();
        buf ^= 1;
    }
#undef STAGE

    // exact per-slice centering correction + sum of squares.
    // C/D mapping (HW-verified): row = (lane>>4)*4 + reg, col = lane&15.
    // acc[f][g][r] = C[a][b], a = wm*128 + f*16 + kg*4 + r, b = wn*64 + g*16 + m
    const float* Si = S + (size_t)s * TOTD + ci * EMB;
    const float* Sj = S + (size_t)s * TOTD + cj * EMB;
    const float* ki = cm + ci * EMB;
    const float* kj = cm + cj * EMB;
    float cb[4], tb[4];
#pragma unroll
    for (int g = 0; g < 4; ++g) {
        int b = wn * 64 + g * 16 + m;
        cb[g] = kj[b];
        tb[g] = Sj[b] - 256.f * cb[g];
    }
    float sq = 0.f;
#pragma unroll
    for (int f = 0; f < 8; ++f)
#pragma unroll
        for (int r = 0; r < 4; ++r) {
            int a = wm * 128 + f * 16 + kg * 4 + r;
            float sa_ = Si[a], ca_ = ki[a];
#pragma unroll
            for (int g = 0; g < 4; ++g) {
                float v = acc[f][g][r] - sa_ * cb[g] - ca_ * tb[g];
                sq += v * v;
            }
        }

    sred[tid] = sq;
    __syncthreads();
    if (tid < 64) {
        float v = 0.f;
#pragma unroll
        for (int c = 0; c < 8; ++c) v += sred[tid + c * 64];
#pragma unroll
        for (int off = 32; off > 0; off >>= 1) v += __shfl_down(v, off);
        if (tid == 0) pp[blockIdx.x] = v;
    }
}

// ---- kernel 4: deterministic final reduction
__global__ __launch_bounds__(256) void finalize_k(const float* __restrict__ pp,
                                                  float* __restrict__ out) {
    __shared__ float sh[256];
    float s = 0.f;
    for (int idx = threadIdx.x; idx < 720; idx += 256) s += pp[idx];
    sh[threadIdx.x] = s;
    __syncthreads();
    for (int stride = 128; stride > 0; stride >>= 1) {
        if (threadIdx.x < stride) sh[threadIdx.x] += sh[threadIdx.x + stride];
        __syncthreads();
    }
    if (threadIdx.x == 0) out[0] = sh[0] * (1.0f / (4095.0f * 4095.0f));
}

extern "C" void kernel_launch(void* const* d_in, const int* in_sizes, int n_in,
                              void* d_out, int out_size, void* d_ws, size_t ws_size,
                              hipStream_t stream) {
    const float* E = (const float*)d_in[0];   // [4096, 2560] f32
    const float* w = (const float*)d_in[1];   // [4096, 1] f32
    float* out = (float*)d_out;
    char* ws = (char*)d_ws;

    // ws layout (bytes):
    //   Gt  : 0         .. 20971520   (2560 x 4096 bf16)
    //   csp : 20971520  .. 21626880   (64 x 2560 f32, per-64-row colsum partials)
    //   S   : 21626880  .. 21790720   (16 x 2560 f32, per-slice colsums)
    //   cm  : 21790720  .. 21800960   (2560 f32, global colmeans)
    //   pp  : 21800960  .. 21803840   (720 f32, per-block partial losses)
    unsigned short* Gt = (unsigned short*)ws;
    float* csp = (float*)(ws + (size_t)20971520);
    float* S   = (float*)(ws + (size_t)21626880);
    float* cm  = (float*)(ws + (size_t)21790720);
    float* pp  = (float*)(ws + (size_t)21800960);

    prep_k<<<dim3(64, 40), 256, 0, stream>>>(E, w, Gt, csp);
    sums_k<<<10, 256, 0, stream>>>(csp, S, cm);
    gram_fro_k<<<720, 512, 0, stream>>>(Gt, S, cm, pp);
    finalize_k<<<1, 256, 0, stream>>>(pp, out);
}

// Round 5
// 49.038 us; speedup vs baseline: 2.6106x; 1.0433x over previous
//
#include <hip/hip_runtime.h>
#include <hip/hip_bf16.h>

#define NN 4096
#define EMB 256
#define NCH 10
#define TOTD 2560  // NCH*EMB

typedef __attribute__((ext_vector_type(8))) short bf16x8;
typedef __attribute__((ext_vector_type(8))) unsigned short u16x8;
typedef __attribute__((ext_vector_type(4))) float f32x4;

#define AS1 __attribute__((address_space(1)))
#define AS3 __attribute__((address_space(3)))

__device__ __forceinline__ void gload_lds16(const void* g, void* l) {
    __builtin_amdgcn_global_load_lds((const AS1 unsigned int*)g,
                                     (AS3 unsigned int*)l, 16, 0, 0);
}

// ---- kernel 1 (fused prep): one pass over E.
// F = w^2 * E ; Gt[d][a] = bf16(F[a][d]) ; csp[ablk][d] = sum_{a in 64-blk} F[a][d]
__global__ __launch_bounds__(256) void prep_k(const float* __restrict__ E,
                                              const float* __restrict__ w,
                                              unsigned short* __restrict__ Gt,
                                              float* __restrict__ csp) {
    __shared__ float tile[64][65];
    const int ab = blockIdx.x, db = blockIdx.y;
    const int a0 = ab * 64, d0 = db * 64;
    const int t = threadIdx.x;
    const int ar = t >> 4, dc = (t & 15) * 4;
#pragma unroll
    for (int r = 0; r < 4; ++r) {
        int a = ar + r * 16;
        float ww = w[a0 + a];
        ww *= ww;
        const float4 v = *reinterpret_cast<const float4*>(E + (size_t)(a0 + a) * TOTD + d0 + dc);
        tile[a][dc + 0] = ww * v.x;
        tile[a][dc + 1] = ww * v.y;
        tile[a][dc + 2] = ww * v.z;
        tile[a][dc + 3] = ww * v.w;
    }
    __syncthreads();
    const int as = (t & 7) * 8;
#pragma unroll
    for (int r = 0; r < 2; ++r) {
        int d = (t >> 3) + r * 32;
        u16x8 u;
#pragma unroll
        for (int e = 0; e < 8; ++e) {
            union { __hip_bfloat16 b; unsigned short s; } cv;
            cv.b = __float2bfloat16(tile[as + e][d]);
            u[e] = cv.s;
        }
        *reinterpret_cast<u16x8*>(Gt + (size_t)(d0 + d) * NN + a0 + as) = u;
    }
    if (t < 64) {
        float s = 0.f;
#pragma unroll 8
        for (int a = 0; a < 64; ++a) s += tile[a][t];
        csp[(size_t)ab * TOTD + d0 + t] = s;
    }
}

// ---- kernel 2: per-slice colsums S[16][2560] and global colmean cm[2560]
__global__ __launch_bounds__(256) void sums_k(const float* __restrict__ csp,
                                              float* __restrict__ S,
                                              float* __restrict__ cm) {
    int d = blockIdx.x * 256 + threadIdx.x;
    float tot = 0.f;
#pragma unroll
    for (int s = 0; s < 16; ++s) {
        float v = 0.f;
#pragma unroll
        for (int b = 0; b < 4; ++b) v += csp[(size_t)(s * 4 + b) * TOTD + d];
        S[(size_t)s * TOTD + d] = v;
        tot += v;
    }
    cm[d] = tot * (1.0f / NN);
}

// ---- kernel 3: 720 blocks = 45 pairs x 16 K-slices (K=256, BK=32).
// Swizzled so each XCD owns 2 slices (slice working set 1.28 MB -> L2-resident):
//   blockIdx = (s&7) + 8*(pr + 45*(s>>3)), bijective over [0,720).
// 3-buffer LDS pipeline, prefetch depth 2, counted s_waitcnt vmcnt(4) + raw
// s_barrier (loads for step t+2 stay in flight across the barrier).
// 8 waves (2Mx4N), wave tile 128x64. Exact per-slice rank-1 centering in
// epilogue, then sum of squares (layout-sensitive correction uses the
// HW-verified C/D mapping; verified absmax 0.0 in rounds 3-4).
__global__ __launch_bounds__(512) void gram_fro_k(const unsigned short* __restrict__ Gt,
                                                  const float* __restrict__ S,
                                                  const float* __restrict__ cm,
                                                  float* __restrict__ pp) {
    const int bx = blockIdx.x;
    const int q = bx >> 3;
    const int pr = q % 45;
    const int s = (bx & 7) + 8 * (q / 45);
    int ci = 0, r0 = pr, cnt = NCH - 1;
    while (r0 >= cnt) { r0 -= cnt; --cnt; ++ci; }
    const int cj = ci + 1 + r0;
    const int k0 = s * 256;

    const int tid = threadIdx.x, wave = tid >> 6, lane = tid & 63;
    const int wm = wave >> 2, wn = wave & 3;
    const int m = lane & 15, kg = lane >> 4;

    __shared__ char lds[98304];   // 3 bufs x [A 16K | B 16K]
    __shared__ float sred[512];

    // staging: issue ii covers rows wave*32 + ii*16 + (lane>>2), lds slot lane&3.
    // global source pre-swizzled: gslot = (lane&3) ^ ((row>>1)&3)
    const int gslot = (lane & 3) ^ ((lane >> 3) & 3);
    const unsigned short* gA = Gt + (size_t)(ci * EMB + wave * 32 + (lane >> 2)) * NN + k0 + gslot * 8;
    const unsigned short* gB = Gt + (size_t)(cj * EMB + wave * 32 + (lane >> 2)) * NN + k0 + gslot * 8;
    const int ldsBase = wave * 2048;  // (wave*32 rows) * 64 B

#define STAGE(buf, t)                                                          \
    do {                                                                       \
        _Pragma("unroll") for (int ii = 0; ii < 2; ++ii) {                     \
            gload_lds16(gA + (size_t)ii * 16 * NN + (t) * 32,                  \
                        lds + (buf) * 32768 + ldsBase + ii * 1024);            \
            gload_lds16(gB + (size_t)ii * 16 * NN + (t) * 32,                  \
                        lds + (buf) * 32768 + 16384 + ldsBase + ii * 1024);    \
        }                                                                      \
    } while (0)

    f32x4 acc[8][4];
#pragma unroll
    for (int f = 0; f < 8; ++f)
#pragma unroll
        for (int g = 0; g < 4; ++g) acc[f][g] = (f32x4){0.f, 0.f, 0.f, 0.f};

    // prologue: stage t=0 and t=1; wait for t=0 (keep t=1 in flight)
    STAGE(0, 0);
    STAGE(1, 1);
    asm volatile("s_waitcnt vmcnt(4)" ::: "memory");
    __builtin_amdgcn_s_barrier();
    __builtin_amdgcn_sched_barrier(0);

    const int slotRd = (kg ^ ((m >> 1) & 3)) * 16;
#pragma unroll
    for (int t = 0; t < 8; ++t) {
        const int buf = t % 3;
        if (t + 2 < 8) STAGE((t + 2) % 3, t + 2);
        const char* Ab = lds + buf * 32768;
        const char* Bb = Ab + 16384;
        bf16x8 af[8], bfr[4];
#pragma unroll
        for (int f = 0; f < 8; ++f)
            af[f] = *reinterpret_cast<const bf16x8*>(Ab + (wm * 128 + f * 16 + m) * 64 + slotRd);
#pragma unroll
        for (int g = 0; g < 4; ++g)
            bfr[g] = *reinterpret_cast<const bf16x8*>(Bb + (wn * 64 + g * 16 + m) * 64 + slotRd);
#pragma unroll
        for (int f = 0; f < 8; ++f)
#pragma unroll
            for (int g = 0; g < 4; ++g)
                acc[f][g] = __builtin_amdgcn_mfma_f32_16x16x32_bf16(af[f], bfr[g], acc[f][g], 0, 0, 0);
        if (t < 7) {
            // drain the oldest 4 loads (the buffer read next step); keep the
            // 4 just-issued (t+2) in flight across the barrier.
            if (t + 2 < 8) asm volatile("s_waitcnt vmcnt(4)" ::: "memory");
            else           asm volatile("s_waitcnt vmcnt(0)" ::: "memory");
            __builtin_amdgcn_s_barrier();
            __builtin_amdgcn_sched_barrier(0);
        }
    }
#undef STAGE

    // exact per-slice centering correction + sum of squares.
    // C/D mapping (HW-verified): row = (lane>>4)*4 + reg, col = lane&15.
    const float* Si = S + (size_t)s * TOTD + ci * EMB;
    const float* Sj = S + (size_t)s * TOTD + cj * EMB;
    const float* ki = cm + ci * EMB;
    const float* kj = cm + cj * EMB;
    float cb[4], tb[4];
#pragma unroll
    for (int g = 0; g < 4; ++g) {
        int b = wn * 64 + g * 16 + m;
        cb[g] = kj[b];
        tb[g] = Sj[b] - 256.f * cb[g];
    }
    float sq = 0.f;
#pragma unroll
    for (int f = 0; f < 8; ++f)
#pragma unroll
        for (int r = 0; r < 4; ++r) {
            int a = wm * 128 + f * 16 + kg * 4 + r;
            float sa_ = Si[a], ca_ = ki[a];
#pragma unroll
            for (int g = 0; g < 4; ++g) {
                float v = acc[f][g][r] - sa_ * cb[g] - ca_ * tb[g];
                sq += v * v;
            }
        }

    sred[tid] = sq;
    __syncthreads();
    if (tid < 64) {
        float v = 0.f;
#pragma unroll
        for (int c = 0; c < 8; ++c) v += sred[tid + c * 64];
#pragma unroll
        for (int off = 32; off > 0; off >>= 1) v += __shfl_down(v, off);
        if (tid == 0) pp[blockIdx.x] = v;
    }
}

// ---- kernel 4: deterministic final reduction
__global__ __launch_bounds__(256) void finalize_k(const float* __restrict__ pp,
                                                  float* __restrict__ out) {
    __shared__ float sh[256];
    float s = 0.f;
    for (int idx = threadIdx.x; idx < 720; idx += 256) s += pp[idx];
    sh[threadIdx.x] = s;
    __syncthreads();
    for (int stride = 128; stride > 0; stride >>= 1) {
        if (threadIdx.x < stride) sh[threadIdx.x] += sh[threadIdx.x + stride];
        __syncthreads();
    }
    if (threadIdx.x == 0) out[0] = sh[0] * (1.0f / (4095.0f * 4095.0f));
}

extern "C" void kernel_launch(void* const* d_in, const int* in_sizes, int n_in,
                              void* d_out, int out_size, void* d_ws, size_t ws_size,
                              hipStream_t stream) {
    const float* E = (const float*)d_in[0];   // [4096, 2560] f32
    const float* w = (const float*)d_in[1];   // [4096, 1] f32
    float* out = (float*)d_out;
    char* ws = (char*)d_ws;

    // ws layout (bytes):
    //   Gt  : 0         .. 20971520   (2560 x 4096 bf16)
    //   csp : 20971520  .. 21626880   (64 x 2560 f32, per-64-row colsum partials)
    //   S   : 21626880  .. 21790720   (16 x 2560 f32, per-slice colsums)
    //   cm  : 21790720  .. 21800960   (2560 f32, global colmeans)
    //   pp  : 21800960  .. 21803840   (720 f32, per-block partial losses)
    unsigned short* Gt = (unsigned short*)ws;
    float* csp = (float*)(ws + (size_t)20971520);
    float* S   = (float*)(ws + (size_t)21626880);
    float* cm  = (float*)(ws + (size_t)21790720);
    float* pp  = (float*)(ws + (size_t)21800960);

    prep_k<<<dim3(64, 40), 256, 0, stream>>>(E, w, Gt, csp);
    sums_k<<<10, 256, 0, stream>>>(csp, S, cm);
    gram_fro_k<<<720, 512, 0, stream>>>(Gt, S, cm, pp);
    finalize_k<<<1, 256, 0, stream>>>(pp, out);
}

// Round 6
// 46.296 us; speedup vs baseline: 2.7653x; 1.0592x over previous
//
#include <hip/hip_runtime.h>
#include <hip/hip_bf16.h>

#define NN 4096
#define EMB 256
#define NCH 10
#define TOTD 2560  // NCH*EMB

typedef __attribute__((ext_vector_type(4))) float f32x4;

#define AS1 __attribute__((address_space(1)))
#define AS3 __attribute__((address_space(3)))

__device__ __forceinline__ void gload_lds16(const void* g, void* l) {
    __builtin_amdgcn_global_load_lds((const AS1 unsigned int*)g,
                                     (AS3 unsigned int*)l, 16, 0, 0);
}

// float -> OCP e4m3fn, RNE, flush |x| < 2^-6 (min normal) to 0.
// Data range |x| <~ 6 << 448, so no saturation/NaN path needed.
__device__ __forceinline__ unsigned int f32_to_e4m3(float x) {
    unsigned int u = __float_as_uint(x);
    if ((u & 0x7FFFFFFFu) < 0x3C800000u) return 0u;   // |x| < 2^-6
    unsigned int r = u + 0x7FFFFu + ((u >> 20) & 1u); // RNE to 3 mantissa bits
    unsigned int s = (u >> 31) << 7;
    unsigned int e = (r >> 23) & 0xFFu;               // f32 exponent after round
    unsigned int m3 = (r >> 20) & 7u;
    return s | ((e - 120u) << 3) | m3;                // e4m3 bias 7: e-127+7
}

// ---- kernel 1 (fused prep): one pass over E.
// F = w^2*E ; Gt8[d][a] = e4m3(F[a][d]) ; csp[ablk][d] = sum_{a in 64-blk} F[a][d]
__global__ __launch_bounds__(256) void prep_k(const float* __restrict__ E,
                                              const float* __restrict__ w,
                                              unsigned char* __restrict__ Gt8,
                                              float* __restrict__ csp) {
    __shared__ float tile[64][65];
    const int ab = blockIdx.x, db = blockIdx.y;
    const int a0 = ab * 64, d0 = db * 64;
    const int t = threadIdx.x;
    const int ar = t >> 4, dc = (t & 15) * 4;
#pragma unroll
    for (int r = 0; r < 4; ++r) {
        int a = ar + r * 16;
        float ww = w[a0 + a];
        ww *= ww;
        const float4 v = *reinterpret_cast<const float4*>(E + (size_t)(a0 + a) * TOTD + d0 + dc);
        tile[a][dc + 0] = ww * v.x;
        tile[a][dc + 1] = ww * v.y;
        tile[a][dc + 2] = ww * v.z;
        tile[a][dc + 3] = ww * v.w;
    }
    __syncthreads();
    const int as = (t & 7) * 8;
#pragma unroll
    for (int r = 0; r < 2; ++r) {
        int d = (t >> 3) + r * 32;
        unsigned int lo = 0, hi = 0;
#pragma unroll
        for (int e = 0; e < 4; ++e) lo |= f32_to_e4m3(tile[as + e][d]) << (8 * e);
#pragma unroll
        for (int e = 0; e < 4; ++e) hi |= f32_to_e4m3(tile[as + 4 + e][d]) << (8 * e);
        *reinterpret_cast<uint2*>(Gt8 + (size_t)(d0 + d) * NN + a0 + as) = make_uint2(lo, hi);
    }
    if (t < 64) {
        float s = 0.f;
#pragma unroll 8
        for (int a = 0; a < 64; ++a) s += tile[a][t];
        csp[(size_t)ab * TOTD + d0 + t] = s;
    }
}

// ---- kernel 2: per-slice colsums S[16][2560] and global colmean cm[2560]
__global__ __launch_bounds__(256) void sums_k(const float* __restrict__ csp,
                                              float* __restrict__ S,
                                              float* __restrict__ cm) {
    int d = blockIdx.x * 256 + threadIdx.x;
    float tot = 0.f;
#pragma unroll
    for (int s = 0; s < 16; ++s) {
        float v = 0.f;
#pragma unroll
        for (int b = 0; b < 4; ++b) v += csp[(size_t)(s * 4 + b) * TOTD + d];
        S[(size_t)s * TOTD + d] = v;
        tot += v;
    }
    cm[d] = tot * (1.0f / NN);
}

// ---- kernel 3: 720 blocks = 45 pairs x 16 K-slices (K=256, BK=32, fp8).
// XCD swizzle: blockIdx = (s&7) + 8*(pr + 45*(s>>3)) -> each XCD owns 2 slices
// (slice working set 2560x256 fp8 = 0.65 MB, L2-resident).
// 4-buffer LDS pipeline, prefetch depth 3, counted vmcnt; 8 waves (2Mx4N),
// wave tile 128x64, mfma_f32_16x16x32_fp8_fp8 (8B fragments).
// LDS tile: [256 rows][32 B]; 16B slot s16 holds global half (s16 ^ ((row>>2)&1))
// -> ds_read_b64 fragments land 4 words/bank uniform (conflict-free).
__global__ __launch_bounds__(512) void gram_fro_k(const unsigned char* __restrict__ Gt8,
                                                  const float* __restrict__ S,
                                                  const float* __restrict__ cm,
                                                  float* __restrict__ pp) {
    const int bx = blockIdx.x;
    const int q = bx >> 3;
    const int pr = q % 45;
    const int s = (bx & 7) + 8 * (q / 45);
    int ci = 0, r0 = pr, cnt = NCH - 1;
    while (r0 >= cnt) { r0 -= cnt; --cnt; ++ci; }
    const int cj = ci + 1 + r0;
    const int k0 = s * 256;

    const int tid = threadIdx.x, wave = tid >> 6, lane = tid & 63;
    const int wm = wave >> 2, wn = wave & 3;
    const int m = lane & 15, kg = lane >> 4;

    __shared__ char lds[65536];   // 4 bufs x [A 8K | B 8K]
    __shared__ float sred[512];

    // staging: lane covers row wave*32 + (lane>>1), 16B slot lane&1.
    // pre-swizzled source half: (lane&1) ^ ((row>>2)&1) = (lane&1)^((lane>>3)&1)
    const int srcoff = ((lane & 1) ^ ((lane >> 3) & 1)) * 16;
    const unsigned char* gA = Gt8 + (size_t)(ci * EMB + wave * 32 + (lane >> 1)) * NN + k0 + srcoff;
    const unsigned char* gB = Gt8 + (size_t)(cj * EMB + wave * 32 + (lane >> 1)) * NN + k0 + srcoff;
    const int ldsW = wave * 1024;   // 32 rows * 32 B

#define STAGE(buf, t)                                                      \
    do {                                                                   \
        gload_lds16(gA + (size_t)(t) * 32, lds + (buf) * 16384 + ldsW);    \
        gload_lds16(gB + (size_t)(t) * 32, lds + (buf) * 16384 + 8192 + ldsW); \
    } while (0)

    f32x4 acc[8][4];
#pragma unroll
    for (int f = 0; f < 8; ++f)
#pragma unroll
        for (int g = 0; g < 4; ++g) acc[f][g] = (f32x4){0.f, 0.f, 0.f, 0.f};

    // prologue: stage t=0,1,2; wait for t=0 (keep 4 loads in flight)
    STAGE(0, 0);
    STAGE(1, 1);
    STAGE(2, 2);
    asm volatile("s_waitcnt vmcnt(4)" ::: "memory");
    __builtin_amdgcn_s_barrier();
    __builtin_amdgcn_sched_barrier(0);

    // fragment read offset within row: 16B slot (kg>>1)^((m>>2)&1), 8B half kg&1
    const int soff = ((kg >> 1) ^ ((m >> 2) & 1)) * 16 + (kg & 1) * 8;
#pragma unroll
    for (int t = 0; t < 8; ++t) {
        const int buf = t & 3;
        if (t + 3 < 8) STAGE((t + 3) & 3, t + 3);
        const char* Ab = lds + buf * 16384;
        const char* Bb = Ab + 8192;
        long av[8], bv[4];
#pragma unroll
        for (int f = 0; f < 8; ++f)
            av[f] = *reinterpret_cast<const long*>(Ab + (wm * 128 + f * 16 + m) * 32 + soff);
#pragma unroll
        for (int g = 0; g < 4; ++g)
            bv[g] = *reinterpret_cast<const long*>(Bb + (wn * 64 + g * 16 + m) * 32 + soff);
#pragma unroll
        for (int f = 0; f < 8; ++f)
#pragma unroll
            for (int g = 0; g < 4; ++g)
                acc[f][g] = __builtin_amdgcn_mfma_f32_16x16x32_fp8_fp8(av[f], bv[g], acc[f][g], 0, 0, 0);
        if (t < 7) {
            // drain loads for the next-read buffer only; keep deeper prefetch in flight
            if (t < 5)      asm volatile("s_waitcnt vmcnt(4)" ::: "memory");
            else if (t == 5) asm volatile("s_waitcnt vmcnt(2)" ::: "memory");
            else             asm volatile("s_waitcnt vmcnt(0)" ::: "memory");
            __builtin_amdgcn_s_barrier();
            __builtin_amdgcn_sched_barrier(0);
        }
    }
#undef STAGE

    // exact per-slice centering correction + sum of squares.
    // C/D mapping (HW-verified, dtype-independent): row=(lane>>4)*4+reg, col=lane&15.
    const float* Si = S + (size_t)s * TOTD + ci * EMB;
    const float* Sj = S + (size_t)s * TOTD + cj * EMB;
    const float* ki = cm + ci * EMB;
    const float* kj = cm + cj * EMB;
    float cb[4], tb[4];
#pragma unroll
    for (int g = 0; g < 4; ++g) {
        int b = wn * 64 + g * 16 + m;
        cb[g] = kj[b];
        tb[g] = Sj[b] - 256.f * cb[g];
    }
    float sq = 0.f;
#pragma unroll
    for (int f = 0; f < 8; ++f)
#pragma unroll
        for (int r = 0; r < 4; ++r) {
            int a = wm * 128 + f * 16 + kg * 4 + r;
            float sa_ = Si[a], ca_ = ki[a];
#pragma unroll
            for (int g = 0; g < 4; ++g) {
                float v = acc[f][g][r] - sa_ * cb[g] - ca_ * tb[g];
                sq += v * v;
            }
        }

    sred[tid] = sq;
    __syncthreads();
    if (tid < 64) {
        float v = 0.f;
#pragma unroll
        for (int c = 0; c < 8; ++c) v += sred[tid + c * 64];
#pragma unroll
        for (int off = 32; off > 0; off >>= 1) v += __shfl_down(v, off);
        if (tid == 0) pp[blockIdx.x] = v;
    }
}

// ---- kernel 4: deterministic final reduction
__global__ __launch_bounds__(256) void finalize_k(const float* __restrict__ pp,
                                                  float* __restrict__ out) {
    __shared__ float sh[256];
    float s = 0.f;
    for (int idx = threadIdx.x; idx < 720; idx += 256) s += pp[idx];
    sh[threadIdx.x] = s;
    __syncthreads();
    for (int stride = 128; stride > 0; stride >>= 1) {
        if (threadIdx.x < stride) sh[threadIdx.x] += sh[threadIdx.x + stride];
        __syncthreads();
    }
    if (threadIdx.x == 0) out[0] = sh[0] * (1.0f / (4095.0f * 4095.0f));
}

extern "C" void kernel_launch(void* const* d_in, const int* in_sizes, int n_in,
                              void* d_out, int out_size, void* d_ws, size_t ws_size,
                              hipStream_t stream) {
    const float* E = (const float*)d_in[0];   // [4096, 2560] f32
    const float* w = (const float*)d_in[1];   // [4096, 1] f32
    float* out = (float*)d_out;
    char* ws = (char*)d_ws;

    // ws layout (bytes):
    //   Gt8 : 0         .. 10485760   (2560 x 4096 fp8 e4m3)
    //   csp : 10485760  .. 11141120   (64 x 2560 f32)
    //   S   : 11141120  .. 11304960   (16 x 2560 f32)
    //   cm  : 11304960  .. 11315200   (2560 f32)
    //   pp  : 11315200  .. 11318080   (720 f32)
    unsigned char* Gt8 = (unsigned char*)ws;
    float* csp = (float*)(ws + (size_t)10485760);
    float* S   = (float*)(ws + (size_t)11141120);
    float* cm  = (float*)(ws + (size_t)11304960);
    float* pp  = (float*)(ws + (size_t)11315200);

    prep_k<<<dim3(64, 40), 256, 0, stream>>>(E, w, Gt8, csp);
    sums_k<<<10, 256, 0, stream>>>(csp, S, cm);
    gram_fro_k<<<720, 512, 0, stream>>>(Gt8, S, cm, pp);
    finalize_k<<<1, 256, 0, stream>>>(pp, out);
}

// Round 7
// 40.051 us; speedup vs baseline: 3.1965x; 1.1559x over previous
//
#include <hip/hip_runtime.h>
#include <hip/hip_bf16.h>

#define NN 4096
#define EMB 256
#define NCH 10
#define TOTD 2560  // NCH*EMB

typedef __attribute__((ext_vector_type(4))) float f32x4;
typedef __attribute__((ext_vector_type(16))) float f32x16;
typedef __attribute__((ext_vector_type(4))) int i32x4;
typedef __attribute__((ext_vector_type(8))) int i32x8;

#define AS1 __attribute__((address_space(1)))
#define AS3 __attribute__((address_space(3)))

__device__ __forceinline__ void gload_lds16(const void* g, void* l) {
    __builtin_amdgcn_global_load_lds((const AS1 unsigned int*)g,
                                     (AS3 unsigned int*)l, 16, 0, 0);
}

// float -> OCP e4m3fn, RNE, flush |x| < 2^-6 (min normal) to 0.
__device__ __forceinline__ unsigned int f32_to_e4m3(float x) {
    unsigned int u = __float_as_uint(x);
    if ((u & 0x7FFFFFFFu) < 0x3C800000u) return 0u;   // |x| < 2^-6
    unsigned int r = u + 0x7FFFFu + ((u >> 20) & 1u); // RNE to 3 mantissa bits
    unsigned int s = (u >> 31) << 7;
    unsigned int e = (r >> 23) & 0xFFu;
    unsigned int m3 = (r >> 20) & 7u;
    return s | ((e - 120u) << 3) | m3;
}

// ---- kernel 1 (fused prep): one pass over E.
__global__ __launch_bounds__(256) void prep_k(const float* __restrict__ E,
                                              const float* __restrict__ w,
                                              unsigned char* __restrict__ Gt8,
                                              float* __restrict__ csp) {
    __shared__ float tile[64][65];
    const int ab = blockIdx.x, db = blockIdx.y;
    const int a0 = ab * 64, d0 = db * 64;
    const int t = threadIdx.x;
    const int ar = t >> 4, dc = (t & 15) * 4;
#pragma unroll
    for (int r = 0; r < 4; ++r) {
        int a = ar + r * 16;
        float ww = w[a0 + a];
        ww *= ww;
        const float4 v = *reinterpret_cast<const float4*>(E + (size_t)(a0 + a) * TOTD + d0 + dc);
        tile[a][dc + 0] = ww * v.x;
        tile[a][dc + 1] = ww * v.y;
        tile[a][dc + 2] = ww * v.z;
        tile[a][dc + 3] = ww * v.w;
    }
    __syncthreads();
    const int as = (t & 7) * 8;
#pragma unroll
    for (int r = 0; r < 2; ++r) {
        int d = (t >> 3) + r * 32;
        unsigned int lo = 0, hi = 0;
#pragma unroll
        for (int e = 0; e < 4; ++e) lo |= f32_to_e4m3(tile[as + e][d]) << (8 * e);
#pragma unroll
        for (int e = 0; e < 4; ++e) hi |= f32_to_e4m3(tile[as + 4 + e][d]) << (8 * e);
        *reinterpret_cast<uint2*>(Gt8 + (size_t)(d0 + d) * NN + a0 + as) = make_uint2(lo, hi);
    }
    if (t < 64) {
        float s = 0.f;
#pragma unroll 8
        for (int a = 0; a < 64; ++a) s += tile[a][t];
        csp[(size_t)ab * TOTD + d0 + t] = s;
    }
}

// ---- kernel 2: per-slice colsums S[16][2560] and global colmean cm[2560]
__global__ __launch_bounds__(256) void sums_k(const float* __restrict__ csp,
                                              float* __restrict__ S,
                                              float* __restrict__ cm) {
    int d = blockIdx.x * 256 + threadIdx.x;
    float tot = 0.f;
#pragma unroll
    for (int s = 0; s < 16; ++s) {
        float v = 0.f;
#pragma unroll
        for (int b = 0; b < 4; ++b) v += csp[(size_t)(s * 4 + b) * TOTD + d];
        S[(size_t)s * TOTD + d] = v;
        tot += v;
    }
    cm[d] = tot * (1.0f / NN);
}

// ---- kernel 3: 720 blocks = 45 pairs x 16 K-slices (K=256, BK=64, MX fp8).
// mfma_scale_f32_32x32x64_f8f6f4 with unit scales (0x7F E8M0 = 1.0) = 2x fp8
// rate. 8 waves (2Mx4N), wave tile 128x64 = 4x2 tiles of 32x32. 3-buffer LDS
// (96KB), prefetch depth 2, counted vmcnt. XCD swizzle as before.
// LDS row = 64B (4 x 16B slots); slot' = slot ^ ((row>>1)&3), achieved via
// pre-swizzled global source (linear gload_lds dest) + swizzled ds_read.
__global__ __launch_bounds__(512, 2) void gram_fro_k(const unsigned char* __restrict__ Gt8,
                                                     const float* __restrict__ S,
                                                     const float* __restrict__ cm,
                                                     float* __restrict__ pp) {
    const int bx = blockIdx.x;
    const int q = bx >> 3;
    const int pr = q % 45;
    const int s = (bx & 7) + 8 * (q / 45);
    int ci = 0, r0 = pr, cnt = NCH - 1;
    while (r0 >= cnt) { r0 -= cnt; --cnt; ++ci; }
    const int cj = ci + 1 + r0;
    const int k0 = s * 256;

    const int tid = threadIdx.x, wave = tid >> 6, lane = tid & 63;
    const int wm = wave >> 2, wn = wave & 3;
    const int l31 = lane & 31, h = lane >> 5;

    __shared__ char lds[98304];   // 3 bufs x [A 16K | B 16K]

    // staging: issue ii covers rows wave*32 + ii*16 + (lane>>2), lds slot lane&3.
    // pre-swizzled source slot: (lane&3) ^ ((row>>1)&3) = (lane&3)^((lane>>3)&3)
    const int gslot = (lane & 3) ^ ((lane >> 3) & 3);
    const unsigned char* gA = Gt8 + (size_t)(ci * EMB + wave * 32 + (lane >> 2)) * NN + k0 + gslot * 16;
    const unsigned char* gB = Gt8 + (size_t)(cj * EMB + wave * 32 + (lane >> 2)) * NN + k0 + gslot * 16;
    const int ldsW = wave * 2048;  // 32 rows * 64 B

#define STAGE(buf, t)                                                              \
    do {                                                                           \
        _Pragma("unroll") for (int ii = 0; ii < 2; ++ii) {                         \
            gload_lds16(gA + (size_t)ii * 16 * NN + (size_t)(t) * 64,              \
                        lds + (buf) * 32768 + ldsW + ii * 1024);                   \
            gload_lds16(gB + (size_t)ii * 16 * NN + (size_t)(t) * 64,              \
                        lds + (buf) * 32768 + 16384 + ldsW + ii * 1024);           \
        }                                                                          \
    } while (0)

    f32x16 acc[4][2];
#pragma unroll
    for (int f = 0; f < 4; ++f)
#pragma unroll
        for (int g = 0; g < 2; ++g)
#pragma unroll
            for (int e = 0; e < 16; ++e) acc[f][g][e] = 0.f;

    STAGE(0, 0);
    STAGE(1, 1);
    asm volatile("s_waitcnt vmcnt(4)" ::: "memory");
    __builtin_amdgcn_s_barrier();
    __builtin_amdgcn_sched_barrier(0);

    // read-side swizzle: x = (row>>1)&3 = (lane>>1)&3 (row base mult of 32)
    const int x2 = (lane >> 1) & 3;
    const int sl0 = ((2 * h) ^ x2) * 16;
    const int sl1 = ((2 * h + 1) ^ x2) * 16;

#pragma unroll
    for (int t = 0; t < 4; ++t) {
        const int buf = t % 3;
        if (t < 2) STAGE((t + 2) % 3, t + 2);
        const char* Ab = lds + buf * 32768;
        const char* Bb = Ab + 16384;
        i32x8 av[4], bv[2];
#pragma unroll
        for (int f = 0; f < 4; ++f) {
            const char* p = Ab + (wm * 128 + f * 32 + l31) * 64;
            i32x4 lo = *reinterpret_cast<const i32x4*>(p + sl0);
            i32x4 hi = *reinterpret_cast<const i32x4*>(p + sl1);
            av[f] = __builtin_shufflevector(lo, hi, 0, 1, 2, 3, 4, 5, 6, 7);
        }
#pragma unroll
        for (int g = 0; g < 2; ++g) {
            const char* p = Bb + (wn * 64 + g * 32 + l31) * 64;
            i32x4 lo = *reinterpret_cast<const i32x4*>(p + sl0);
            i32x4 hi = *reinterpret_cast<const i32x4*>(p + sl1);
            bv[g] = __builtin_shufflevector(lo, hi, 0, 1, 2, 3, 4, 5, 6, 7);
        }
#pragma unroll
        for (int f = 0; f < 4; ++f)
#pragma unroll
            for (int g = 0; g < 2; ++g)
                acc[f][g] = __builtin_amdgcn_mfma_scale_f32_32x32x64_f8f6f4(
                    av[f], bv[g], acc[f][g], 0, 0,
                    0, (int)0x7F7F7F7F, 0, (int)0x7F7F7F7F);
        if (t < 3) {
            if (t < 2) asm volatile("s_waitcnt vmcnt(4)" ::: "memory");
            else       asm volatile("s_waitcnt vmcnt(0)" ::: "memory");
            __builtin_amdgcn_s_barrier();
            __builtin_amdgcn_sched_barrier(0);
        }
    }
#undef STAGE

    // exact per-slice centering correction + sum of squares.
    // C/D 32x32 mapping (HW-verified m74/m101, dtype-independent m121-128):
    //   a_row = (reg&3) + 8*(reg>>2) + 4*(lane>>5), b_col = lane&31
    const float* Si = S + (size_t)s * TOTD + ci * EMB;
    const float* Sj = S + (size_t)s * TOTD + cj * EMB;
    const float* ki = cm + ci * EMB;
    const float* kj = cm + cj * EMB;
    float cb[2], tb[2];
#pragma unroll
    for (int g = 0; g < 2; ++g) {
        int b = wn * 64 + g * 32 + l31;
        cb[g] = kj[b];
        tb[g] = Sj[b] - 256.f * cb[g];
    }
    float sq = 0.f;
#pragma unroll
    for (int f = 0; f < 4; ++f) {
        const int abase = wm * 128 + f * 32 + 4 * h;
#pragma unroll
        for (int qd = 0; qd < 4; ++qd) {
            const f32x4 sa = *reinterpret_cast<const f32x4*>(Si + abase + 8 * qd);
            const f32x4 ka = *reinterpret_cast<const f32x4*>(ki + abase + 8 * qd);
#pragma unroll
            for (int g = 0; g < 2; ++g)
#pragma unroll
                for (int e = 0; e < 4; ++e) {
                    float v = acc[f][g][qd * 4 + e] - sa[e] * cb[g] - ka[e] * tb[g];
                    sq += v * v;
                }
        }
    }

    __syncthreads();               // LDS buffers dead; reuse for reduction
    float* sred = (float*)lds;
    sred[tid] = sq;
    __syncthreads();
    if (tid < 64) {
        float v = 0.f;
#pragma unroll
        for (int c = 0; c < 8; ++c) v += sred[tid + c * 64];
#pragma unroll
        for (int off = 32; off > 0; off >>= 1) v += __shfl_down(v, off);
        if (tid == 0) pp[blockIdx.x] = v;
    }
}

// ---- kernel 4: deterministic final reduction
__global__ __launch_bounds__(256) void finalize_k(const float* __restrict__ pp,
                                                  float* __restrict__ out) {
    __shared__ float sh[256];
    float s = 0.f;
    for (int idx = threadIdx.x; idx < 720; idx += 256) s += pp[idx];
    sh[threadIdx.x] = s;
    __syncthreads();
    for (int stride = 128; stride > 0; stride >>= 1) {
        if (threadIdx.x < stride) sh[threadIdx.x] += sh[threadIdx.x + stride];
        __syncthreads();
    }
    if (threadIdx.x == 0) out[0] = sh[0] * (1.0f / (4095.0f * 4095.0f));
}

extern "C" void kernel_launch(void* const* d_in, const int* in_sizes, int n_in,
                              void* d_out, int out_size, void* d_ws, size_t ws_size,
                              hipStream_t stream) {
    const float* E = (const float*)d_in[0];   // [4096, 2560] f32
    const float* w = (const float*)d_in[1];   // [4096, 1] f32
    float* out = (float*)d_out;
    char* ws = (char*)d_ws;

    // ws layout (bytes):
    //   Gt8 : 0         .. 10485760   (2560 x 4096 fp8 e4m3)
    //   csp : 10485760  .. 11141120   (64 x 2560 f32)
    //   S   : 11141120  .. 11304960   (16 x 2560 f32)
    //   cm  : 11304960  .. 11315200   (2560 f32)
    //   pp  : 11315200  .. 11318080   (720 f32)
    unsigned char* Gt8 = (unsigned char*)ws;
    float* csp = (float*)(ws + (size_t)10485760);
    float* S   = (float*)(ws + (size_t)11141120);
    float* cm  = (float*)(ws + (size_t)11304960);
    float* pp  = (float*)(ws + (size_t)11315200);

    prep_k<<<dim3(64, 40), 256, 0, stream>>>(E, w, Gt8, csp);
    sums_k<<<10, 256, 0, stream>>>(csp, S, cm);
    gram_fro_k<<<720, 512, 0, stream>>>(Gt8, S, cm, pp);
    finalize_k<<<1, 256, 0, stream>>>(pp, out);
}